// Round 2
// baseline (1946.782 us; speedup 1.0000x reference)
//
#include <hip/hip_runtime.h>

#define NE 128
#define NI 32
#define NT 160   // NE + NI
#define NC 10
#define BB 512
#define LL 64
#define DD 784
#define MM (BB*LL)

// ws layout (float offsets)
#define G_OFF   0
#define G_SZ    (NT*NT)            // 25600
#define WXT_OFF (G_OFF + G_SZ)
#define WXT_SZ  (DD*NT)            // 125440
#define U_OFF   (WXT_OFF + WXT_SZ) // 151040
#define U_SZ    (MM*NT)            // 5242880

// out layout (float offsets)
#define O_LOGITS 0
#define O_LAST   327680
#define O_RE     332800
#define O_RI     4527104
#define O_BALE   5575680
#define O_BALI   9769984

// ---------------------------------------------------------------------------
// Prep: Dale-rectified combined recurrent matrix G[k][j] and WxT[d][j].
// ---------------------------------------------------------------------------
__global__ void prep_kernel(const float* __restrict__ Wxe, const float* __restrict__ Wxi,
                            const float* __restrict__ Wee, const float* __restrict__ Wie,
                            const float* __restrict__ Wei, const float* __restrict__ Wii,
                            float* __restrict__ ws) {
  int idx = blockIdx.x * blockDim.x + threadIdx.x;
  const int total = G_SZ + WXT_SZ;
  if (idx >= total) return;
  if (idx < G_SZ) {
    int k = idx / NT, j = idx % NT;
    float g;
    if (j < NE) {
      if (k < NE) g =  fmaxf(Wee[j*NE + k], 0.f);
      else        g = -fmaxf(Wie[j*NI + (k-NE)], 0.f);
    } else {
      int ji = j - NE;
      if (k < NE) g =  fmaxf(Wei[ji*NE + k], 0.f);
      else        g = -fmaxf(Wii[ji*NI + (k-NE)], 0.f);
    }
    ws[G_OFF + k*NT + j] = g;
  } else {
    int t = idx - G_SZ;
    int d = t / NT, j = t % NT;
    float v = (j < NE) ? fmaxf(Wxe[j*DD + d], 0.f)
                       : fmaxf(Wxi[(j-NE)*DD + d], 0.f);
    ws[WXT_OFF + d*NT + j] = v;
  }
}

// ---------------------------------------------------------------------------
// GEMM v2: U[m][j] += X[m][:] @ WxT[:][j].  512 blocks = 128 m-tiles x 4 k-splits.
// Block: 256 rows x 160 cols x K=196 (7 tiles of 28). Thread: 16 rows x 10 cols.
// xs XOR-swizzled (4 ty-row addrs hit disjoint bank groups); wt tx-stride 11
// float4s (2-way max = free). 51.7 KB LDS -> 2 blocks/CU. atomicAdd epilogue.
// ---------------------------------------------------------------------------
__global__ __launch_bounds__(256, 2) void gemm_kernel(const float* __restrict__ X,
                                                      const float* __restrict__ ws,
                                                      float* __restrict__ U) {
  __shared__ float xs[256 * 32];      // [row][8 swizzled float4 slots] 32 KB
  __shared__ float wtL[7 * 176 * 4];  // [k4][tx*11+c][kk] float4 units, 19.7 KB
  const int tid = threadIdx.x;
  const int tx = tid & 15, ty = tid >> 4;
  const int mt = blockIdx.x >> 2;
  const int kq = blockIdx.x & 3;
  const int m0 = mt * 256;
  const int kbase = kq * 196;
  const float* WxT = ws + WXT_OFF;
  const int shift = 2 * (ty & 3);

  float acc[16][10];
  #pragma unroll
  for (int i = 0; i < 16; ++i)
    #pragma unroll
    for (int c = 0; c < 10; ++c) acc[i][c] = 0.f;

  for (int t = 0; t < 7; ++t) {
    const int k0 = kbase + t * 28;
    __syncthreads();
    // stage X tile: 256 rows x 28 floats, ~9 rows per wave-instr, 112B runs
    #pragma unroll
    for (int n = 0; n < 7; ++n) {
      int i = tid + n * 256;          // 0..1791
      int r = i / 7, c4 = i - r * 7;
      float4 v = *(const float4*)(X + (size_t)(m0 + r) * DD + k0 + c4 * 4);
      int slot = (c4 + 2 * ((r >> 4) & 3)) & 7;
      *(float4*)(xs + r * 32 + slot * 4) = v;
    }
    // stage W tile transposed to [k4][tx*11+c][kk]
    #pragma unroll
    for (int n = 0; n < 5; ++n) {
      int i = tid + n * 256;
      if (i < 28 * 40) {
        int d = i / 40, j4 = i - d * 40;
        float4 v = *(const float4*)(WxT + (size_t)(k0 + d) * NT + j4 * 4);
        int k4 = d >> 2, kk = d & 3;
        float vv[4] = {v.x, v.y, v.z, v.w};
        #pragma unroll
        for (int e = 0; e < 4; ++e) {
          int j = j4 * 4 + e;
          int tx2 = j / 10, c2 = j - tx2 * 10;
          wtL[(k4 * 176 + tx2 * 11 + c2) * 4 + kk] = vv[e];
        }
      }
    }
    __syncthreads();
    const float4* wt4p = (const float4*)wtL;
    #pragma unroll
    for (int kk4 = 0; kk4 < 7; ++kk4) {
      float4 wv[10];
      #pragma unroll
      for (int c = 0; c < 10; ++c)
        wv[c] = wt4p[kk4 * 176 + tx * 11 + c];
      const int slot = ((kk4 + shift) & 7) * 4;
      #pragma unroll
      for (int qq = 0; qq < 4; ++qq) {
        float4 xv[4];
        #pragma unroll
        for (int e = 0; e < 4; ++e)
          xv[e] = *(const float4*)(xs + (ty * 16 + qq * 4 + e) * 32 + slot);
        #pragma unroll
        for (int e = 0; e < 4; ++e)
          #pragma unroll
          for (int c = 0; c < 10; ++c)
            acc[qq * 4 + e][c] += xv[e].x * wv[c].x + xv[e].y * wv[c].y
                                + xv[e].z * wv[c].z + xv[e].w * wv[c].w;
      }
    }
  }
  #pragma unroll
  for (int i = 0; i < 16; ++i)
    #pragma unroll
    for (int c = 0; c < 10; ++c)
      atomicAdd(&U[(size_t)(m0 + ty * 16 + i) * NT + tx * 10 + c], acc[i][c]);
}

// ---------------------------------------------------------------------------
// Recurrent scan v2. 256 blocks x 256 threads, 2 rows/block, G in registers.
// ONE barrier per step (parity-buffered rbuf/balbuf); step-l outputs stored at
// top of step l+1 (full dot phase to retire before the barrier drain); owner
// lanes prefetch next step's U into registers one step ahead.
// ---------------------------------------------------------------------------
__global__ __launch_bounds__(256, 1) void recur_kernel(
    const float* __restrict__ ws,
    const float* __restrict__ be, const float* __restrict__ bi,
    float* __restrict__ out) {
  __shared__ float rbuf[2][2][NT];    // [parity][row][j]
  __shared__ float balbuf[2][2][NT];
  __shared__ float biasL[NT];

  const int tid  = threadIdx.x;
  const int lane = tid & 63;
  const int wave = tid >> 6;
  const int jc   = (wave << 3) | (lane & 7);  // 0..31
  const int kc   = (lane >> 3) & 7;           // 0..7
  const int j0   = jc * 5;
  const int k0   = kc * 20;
  const int b0   = blockIdx.x * 2;

  const float* G = ws + G_OFF;
  const float* U = ws + U_OFF;

  float g[20][5];
  #pragma unroll
  for (int kk = 0; kk < 20; ++kk)
    #pragma unroll
    for (int c = 0; c < 5; ++c)
      g[kk][c] = G[(size_t)(k0 + kk) * NT + j0 + c];

  if (tid < NT) biasL[tid] = (tid < NE) ? be[tid] : bi[tid - NE];
  for (int i = tid; i < 2 * 2 * NT; i += 256) (&rbuf[0][0][0])[i] = 0.f;

  const int row = (kc < 2) ? kc : 0;
  float u[5];
  if (kc < 2) {
    const size_t ub = ((size_t)(b0 + row) * LL + 0) * NT + j0;
    #pragma unroll
    for (int c = 0; c < 5; ++c) u[c] = U[ub + c];
  }
  float s[5];
  #pragma unroll
  for (int c = 0; c < 5; ++c) s[c] = 0.f;

  __syncthreads();

  for (int l = 0; l < LL; ++l) {
    const int p = l & 1;
    // ---- store step l-1 outputs (issued early; whole dot phase to drain) ----
    if (l > 0) {
      const int lm = l - 1;
      const int orow = tid >> 7, jj = tid & 127;
      const size_t ob = (size_t)(b0 + orow) * LL + lm;
      out[O_RE   + ob * NE + jj] = rbuf[p][orow][jj];
      out[O_BALE + ob * NE + jj] = balbuf[p][orow][jj];
      if (tid < 64) {
        const int orow2 = tid >> 5, j2 = tid & 31;
        const size_t ob2 = (size_t)(b0 + orow2) * LL + lm;
        out[O_RI   + ob2 * NI + j2] = rbuf[p][orow2][NE + j2];
        out[O_BALI + ob2 * NI + j2] = balbuf[p][orow2][NE + j2];
      }
    }
    // ---- prefetch next step's U (owners) ----
    float nu[5];
    if (kc < 2 && l + 1 < LL) {
      const size_t nb = ((size_t)(b0 + row) * LL + (l + 1)) * NT + j0;
      #pragma unroll
      for (int c = 0; c < 5; ++c) nu[c] = U[nb + c];
    }
    // ---- partial recurrent dots over this thread's k-chunk ----
    float a0[5], a1[5];
    #pragma unroll
    for (int c = 0; c < 5; ++c) { a0[c] = 0.f; a1[c] = 0.f; }
    #pragma unroll
    for (int kk4 = 0; kk4 < 5; ++kk4) {
      float4 rv0 = *(const float4*)(&rbuf[p][0][k0 + kk4 * 4]);
      float4 rv1 = *(const float4*)(&rbuf[p][1][k0 + kk4 * 4]);
      #pragma unroll
      for (int c = 0; c < 5; ++c) {
        a0[c] += rv0.x * g[kk4*4+0][c] + rv0.y * g[kk4*4+1][c]
               + rv0.z * g[kk4*4+2][c] + rv0.w * g[kk4*4+3][c];
        a1[c] += rv1.x * g[kk4*4+0][c] + rv1.y * g[kk4*4+1][c]
               + rv1.z * g[kk4*4+2][c] + rv1.w * g[kk4*4+3][c];
      }
    }
    // ---- butterfly reduce over kc (lane bits 3..5) ----
    #pragma unroll
    for (int c = 0; c < 5; ++c) {
      float v0 = a0[c], v1 = a1[c];
      v0 += __shfl_xor(v0, 8, 64);  v1 += __shfl_xor(v1, 8, 64);
      v0 += __shfl_xor(v0, 16, 64); v1 += __shfl_xor(v1, 16, 64);
      v0 += __shfl_xor(v0, 32, 64); v1 += __shfl_xor(v1, 32, 64);
      a0[c] = v0; a1[c] = v1;
    }
    // ---- owner lanes update state, write next-parity buffers ----
    if (kc < 2) {
      #pragma unroll
      for (int c = 0; c < 5; ++c) {
        float accv = (kc == 0) ? a0[c] : a1[c];
        float bal = accv + u[c];
        balbuf[1 - p][row][j0 + c] = bal;
        float sn = 0.5f * (s[c] + bal + biasL[j0 + c]);
        s[c] = sn;
        rbuf[1 - p][row][j0 + c] = fmaxf(sn, 0.f);
      }
      #pragma unroll
      for (int c = 0; c < 5; ++c) u[c] = nu[c];
    }
    __syncthreads();
  }
  // ---- final store: step 63 outputs live in parity-0 buffers ----
  {
    const int orow = tid >> 7, jj = tid & 127;
    const size_t ob = (size_t)(b0 + orow) * LL + 63;
    out[O_RE   + ob * NE + jj] = rbuf[0][orow][jj];
    out[O_BALE + ob * NE + jj] = balbuf[0][orow][jj];
    if (tid < 64) {
      const int orow2 = tid >> 5, j2 = tid & 31;
      const size_t ob2 = (size_t)(b0 + orow2) * LL + 63;
      out[O_RI   + ob2 * NI + j2] = rbuf[0][orow2][NE + j2];
      out[O_BALI + ob2 * NI + j2] = balbuf[0][orow2][NE + j2];
    }
  }
}

// ---------------------------------------------------------------------------
// Logits: [32768 x 128] @ Wro^T + bro. One thread per (m, class).
// ---------------------------------------------------------------------------
__global__ __launch_bounds__(256) void logits_kernel(const float* __restrict__ Wro,
                                                     const float* __restrict__ bro,
                                                     float* __restrict__ out) {
  __shared__ float WroL[NC * 132];   // row-stride 132: lanes' c*132 differ mod 32
  __shared__ float broL[NC];
  const int tid = threadIdx.x;
  for (int i = tid; i < NC * NE; i += 256) {
    int c = i >> 7, k = i & 127;
    WroL[c * 132 + k] = Wro[i];
  }
  if (tid < NC) broL[tid] = bro[tid];
  __syncthreads();
  const int idx = blockIdx.x * 256 + tid;   // 0..327679 exact
  const int m = idx / 10, c = idx - m * 10;
  const float* re = out + O_RE + (size_t)m * NE;
  float v = broL[c];
  #pragma unroll
  for (int t4 = 0; t4 < 32; ++t4) {
    float4 rv = *(const float4*)(re + t4 * 4);
    float4 wv = *(const float4*)(&WroL[c * 132 + t4 * 4]);
    v += rv.x * wv.x + rv.y * wv.y + rv.z * wv.z + rv.w * wv.w;
  }
  out[O_LOGITS + (size_t)m * NC + c] = v;
  if ((m & 63) == 63) out[O_LAST + (size_t)(m >> 6) * NC + c] = v;
}

extern "C" void kernel_launch(void* const* d_in, const int* in_sizes, int n_in,
                              void* d_out, int out_size, void* d_ws, size_t ws_size,
                              hipStream_t stream) {
  const float* x   = (const float*)d_in[0];
  const float* Wxe = (const float*)d_in[1];
  const float* Wxi = (const float*)d_in[2];
  const float* Wee = (const float*)d_in[3];
  const float* Wie = (const float*)d_in[4];
  const float* Wei = (const float*)d_in[5];
  const float* Wii = (const float*)d_in[6];
  const float* be  = (const float*)d_in[7];
  const float* bi  = (const float*)d_in[8];
  const float* Wro = (const float*)d_in[9];
  const float* bro = (const float*)d_in[10];
  float* ws  = (float*)d_ws;
  float* out = (float*)d_out;

  hipMemsetAsync(ws + U_OFF, 0, (size_t)U_SZ * sizeof(float), stream);
  hipLaunchKernelGGL(prep_kernel, dim3((G_SZ + WXT_SZ + 255)/256), dim3(256), 0, stream,
                     Wxe, Wxi, Wee, Wie, Wei, Wii, ws);
  hipLaunchKernelGGL(gemm_kernel, dim3(512), dim3(256), 0, stream,
                     x, ws, ws + U_OFF);
  hipLaunchKernelGGL(recur_kernel, dim3(BB/2), dim3(256), 0, stream,
                     ws, be, bi, out);
  hipLaunchKernelGGL(logits_kernel, dim3(MM * NC / 256), dim3(256), 0, stream,
                     Wro, bro, out);
}

// Round 4
// 1300.350 us; speedup vs baseline: 1.4971x; 1.4971x over previous
//
#include <hip/hip_runtime.h>

#define NE 128
#define NI 32
#define NT 160   // NE + NI
#define NC 10
#define BB 512
#define LL 64
#define DD 784
#define MM (BB*LL)

// ws layout (float offsets)
#define G_OFF   0
#define G_SZ    (NT*NT)              // 25600
#define WT4_OFF (G_OFF + G_SZ)
#define WT4_SZ  (DD*NT)              // 125440, layout [k4][j][4]
#define U_OFF   (WT4_OFF + WT4_SZ)   // 151040
#define U_SZ    (MM*NT)              // 5242880

// out layout (float offsets)
#define O_LOGITS 0
#define O_LAST   327680
#define O_RE     332800
#define O_RI     4527104
#define O_BALE   5575680
#define O_BALI   9769984

// LDS-only barrier: publish ds_writes (lgkmcnt) without draining global
// stores/loads (vmcnt) — __syncthreads() would emit s_waitcnt vmcnt(0) and
// serialize on every in-flight output store each step.
#define LDS_BARRIER() asm volatile("s_waitcnt lgkmcnt(0)\n\ts_barrier" ::: "memory")

// ---------------------------------------------------------------------------
// Prep: Dale-rectified recurrent matrix G[k][j] and input weights pre-
// transposed to WT4[k4][j][kk] (so GEMM staging is a contiguous float4 copy).
// ---------------------------------------------------------------------------
__global__ void prep_kernel(const float* __restrict__ Wxe, const float* __restrict__ Wxi,
                            const float* __restrict__ Wee, const float* __restrict__ Wie,
                            const float* __restrict__ Wei, const float* __restrict__ Wii,
                            float* __restrict__ ws) {
  int idx = blockIdx.x * blockDim.x + threadIdx.x;
  const int total = G_SZ + WT4_SZ;
  if (idx >= total) return;
  if (idx < G_SZ) {
    int k = idx / NT, j = idx % NT;
    float g;
    if (j < NE) {
      if (k < NE) g =  fmaxf(Wee[j*NE + k], 0.f);
      else        g = -fmaxf(Wie[j*NI + (k-NE)], 0.f);
    } else {
      int ji = j - NE;
      if (k < NE) g =  fmaxf(Wei[ji*NE + k], 0.f);
      else        g = -fmaxf(Wii[ji*NI + (k-NE)], 0.f);
    }
    ws[G_OFF + k*NT + j] = g;
  } else {
    int t = idx - G_SZ;
    int d = t / NT, j = t % NT;
    float v = (j < NE) ? fmaxf(Wxe[j*DD + d], 0.f)
                       : fmaxf(Wxi[(j-NE)*DD + d], 0.f);
    ws[WT4_OFF + ((size_t)(d >> 2) * NT + j) * 4 + (d & 3)] = v;
  }
}

// ---------------------------------------------------------------------------
// GEMM v3.1: U[m][j] = X[m][:] @ Wx^T.  256 blocks (1/CU), m-tile 128, full K.
// Thread tile 8 rows x 10 cols; K tiles of 28, register-prefetch double-
// buffered LDS, one barrier per tile. xs slot-XOR swizzle + wt stride-11
// float4 padding -> conflict-free (<=2-way) reads. No atomics.
// FIX vs v3: W tile is 1120 float4s (28k x 160j), not 280 — wr[5], f<1120.
// ---------------------------------------------------------------------------
__global__ __launch_bounds__(256, 1) void gemm_kernel(const float* __restrict__ X,
                                                      const float* __restrict__ ws,
                                                      float* __restrict__ U) {
  __shared__ float xs[2][128 * 32];     // [buf][row][8 swizzled float4 slots] 2x16 KB
  __shared__ float wt[2][7 * 176 * 4];  // [buf][k4][tx*11+c][kk] float4 units 2x19.7 KB
  const int tid = threadIdx.x;
  const int tx = tid & 15, ty = tid >> 4;   // ty 0..15, 8 rows each
  const int m0 = blockIdx.x * 128;
  const float4* WT4 = (const float4*)(ws + WT4_OFF);
  const int shift = 2 * (ty & 3);

  float acc[8][10];
  #pragma unroll
  for (int i = 0; i < 8; ++i)
    #pragma unroll
    for (int c = 0; c < 10; ++c) acc[i][c] = 0.f;

  float4 xr[4], wr[5];

  // ---- prologue: load tile 0 into regs, write LDS buf 0 ----
  {
    #pragma unroll
    for (int n = 0; n < 4; ++n) {
      int i = tid + n * 256;
      if (i < 896) {
        int r = i / 7, c4 = i - r * 7;
        xr[n] = *(const float4*)(X + (size_t)(m0 + r) * DD + c4 * 4);
      }
    }
    #pragma unroll
    for (int n = 0; n < 5; ++n) {
      int f = tid + n * 256;
      if (f < 1120) wr[n] = WT4[f];
    }
    #pragma unroll
    for (int n = 0; n < 4; ++n) {
      int i = tid + n * 256;
      if (i < 896) {
        int r = i / 7, c4 = i - r * 7;
        int slot = (c4 + 2 * ((r >> 3) & 3)) & 7;
        *(float4*)(xs[0] + r * 32 + slot * 4) = xr[n];
      }
    }
    #pragma unroll
    for (int n = 0; n < 5; ++n) {
      int f = tid + n * 256;
      if (f < 1120) {
        int k4r = f / 160, j = f - k4r * 160;
        int tx2 = j / 10, c2 = j - tx2 * 10;
        ((float4*)wt[0])[k4r * 176 + tx2 * 11 + c2] = wr[n];
      }
    }
    __syncthreads();
  }

  for (int t = 0; t < 28; ++t) {
    const int cur = t & 1;
    // ---- issue global loads for tile t+1 (overlap with compute) ----
    if (t < 27) {
      const int k0 = (t + 1) * 28;
      #pragma unroll
      for (int n = 0; n < 4; ++n) {
        int i = tid + n * 256;
        if (i < 896) {
          int r = i / 7, c4 = i - r * 7;
          xr[n] = *(const float4*)(X + (size_t)(m0 + r) * DD + k0 + c4 * 4);
        }
      }
      #pragma unroll
      for (int n = 0; n < 5; ++n) {
        int f = tid + n * 256;
        if (f < 1120) wr[n] = WT4[(size_t)(t + 1) * 1120 + f];
      }
    }
    // ---- compute on buffer cur ----
    const float* xsc = xs[cur];
    const float4* wp = (const float4*)wt[cur];
    #pragma unroll
    for (int kk4 = 0; kk4 < 7; ++kk4) {
      float4 wv[10];
      #pragma unroll
      for (int c = 0; c < 10; ++c)
        wv[c] = wp[kk4 * 176 + tx * 11 + c];
      const int slot4 = ((kk4 + shift) & 7) * 4;
      float4 xv[8];
      #pragma unroll
      for (int e = 0; e < 8; ++e)
        xv[e] = *(const float4*)(xsc + (ty * 8 + e) * 32 + slot4);
      #pragma unroll
      for (int e = 0; e < 8; ++e)
        #pragma unroll
        for (int c = 0; c < 10; ++c)
          acc[e][c] += xv[e].x * wv[c].x + xv[e].y * wv[c].y
                     + xv[e].z * wv[c].z + xv[e].w * wv[c].w;
    }
    // ---- write prefetched tile t+1 into the other buffer ----
    if (t < 27) {
      const int nb = 1 - cur;
      #pragma unroll
      for (int n = 0; n < 4; ++n) {
        int i = tid + n * 256;
        if (i < 896) {
          int r = i / 7, c4 = i - r * 7;
          int slot = (c4 + 2 * ((r >> 3) & 3)) & 7;
          *(float4*)(xs[nb] + r * 32 + slot * 4) = xr[n];
        }
      }
      #pragma unroll
      for (int n = 0; n < 5; ++n) {
        int f = tid + n * 256;
        if (f < 1120) {
          int k4r = f / 160, j = f - k4r * 160;
          int tx2 = j / 10, c2 = j - tx2 * 10;
          ((float4*)wt[nb])[k4r * 176 + tx2 * 11 + c2] = wr[n];
        }
      }
    }
    __syncthreads();
  }

  // ---- epilogue: direct stores (float2; tx*10 is 8B- but not 16B-aligned) ----
  #pragma unroll
  for (int e = 0; e < 8; ++e) {
    float* base = U + (size_t)(m0 + ty * 8 + e) * NT + tx * 10;
    #pragma unroll
    for (int c2 = 0; c2 < 5; ++c2) {
      float2 v = make_float2(acc[e][c2 * 2], acc[e][c2 * 2 + 1]);
      *(float2*)(base + c2 * 2) = v;
    }
  }
}

// ---------------------------------------------------------------------------
// Recurrent scan v3. 512 blocks x 256 threads, ONE batch row per block
// (2 blocks/CU so two rows' steps interleave). G in registers. One LDS-only
// barrier per step (no vmcnt drain); output stores fire-and-forget; owner
// lanes prefetch next step's U one step ahead.
// ---------------------------------------------------------------------------
__global__ __launch_bounds__(256, 2) void recur_kernel(
    const float* __restrict__ ws,
    const float* __restrict__ be, const float* __restrict__ bi,
    float* __restrict__ out) {
  __shared__ float rbuf[2][NT];       // [parity][j]
  __shared__ float balbuf[2][NT];
  __shared__ float biasL[NT];

  const int tid  = threadIdx.x;
  const int lane = tid & 63;
  const int wave = tid >> 6;
  const int jc   = (wave << 3) | (lane & 7);  // 0..31
  const int kc   = (lane >> 3) & 7;           // 0..7
  const int j0   = jc * 5;
  const int k0   = kc * 20;
  const int b    = blockIdx.x;

  const float* G = ws + G_OFF;
  const float* U = ws + U_OFF;

  float g[20][5];
  #pragma unroll
  for (int kk = 0; kk < 20; ++kk)
    #pragma unroll
    for (int c = 0; c < 5; ++c)
      g[kk][c] = G[(size_t)(k0 + kk) * NT + j0 + c];

  if (tid < NT) biasL[tid] = (tid < NE) ? be[tid] : bi[tid - NE];
  for (int i = tid; i < 2 * NT; i += 256) (&rbuf[0][0])[i] = 0.f;

  const bool owner = (kc == 0);
  float u[5];
  if (owner) {
    const size_t ub = ((size_t)b * LL) * NT + j0;
    #pragma unroll
    for (int c = 0; c < 5; ++c) u[c] = U[ub + c];
  }
  float s[5];
  #pragma unroll
  for (int c = 0; c < 5; ++c) s[c] = 0.f;

  __syncthreads();

  for (int l = 0; l < LL; ++l) {
    const int p = l & 1;
    // ---- store step l-1 outputs (no barrier depends on these) ----
    if (l > 0) {
      const size_t ob = (size_t)b * LL + (l - 1);
      if (tid < NE) {
        out[O_RE   + ob * NE + tid] = rbuf[p][tid];
        out[O_BALE + ob * NE + tid] = balbuf[p][tid];
      } else if (tid < NT) {
        const int j2 = tid - NE;
        out[O_RI   + ob * NI + j2] = rbuf[p][NE + j2];
        out[O_BALI + ob * NI + j2] = balbuf[p][NE + j2];
      }
    }
    // ---- prefetch next step's U (owners) ----
    float nu[5];
    if (owner && l + 1 < LL) {
      const size_t nb = ((size_t)b * LL + (l + 1)) * NT + j0;
      #pragma unroll
      for (int c = 0; c < 5; ++c) nu[c] = U[nb + c];
    }
    // ---- partial dots over this thread's k-chunk ----
    float a[5];
    #pragma unroll
    for (int c = 0; c < 5; ++c) a[c] = 0.f;
    #pragma unroll
    for (int kk4 = 0; kk4 < 5; ++kk4) {
      float4 rv = *(const float4*)(&rbuf[p][k0 + kk4 * 4]);
      #pragma unroll
      for (int c = 0; c < 5; ++c)
        a[c] += rv.x * g[kk4*4+0][c] + rv.y * g[kk4*4+1][c]
              + rv.z * g[kk4*4+2][c] + rv.w * g[kk4*4+3][c];
    }
    // ---- butterfly reduce over kc (lane bits 3..5) ----
    #pragma unroll
    for (int c = 0; c < 5; ++c) {
      float v = a[c];
      v += __shfl_xor(v, 8, 64);
      v += __shfl_xor(v, 16, 64);
      v += __shfl_xor(v, 32, 64);
      a[c] = v;
    }
    // ---- owner lanes update state, write next-parity buffers ----
    if (owner) {
      #pragma unroll
      for (int c = 0; c < 5; ++c) {
        float bal = a[c] + u[c];
        balbuf[1 - p][j0 + c] = bal;
        float sn = 0.5f * (s[c] + bal + biasL[j0 + c]);
        s[c] = sn;
        rbuf[1 - p][j0 + c] = fmaxf(sn, 0.f);
      }
      #pragma unroll
      for (int c = 0; c < 5; ++c) u[c] = nu[c];
    }
    LDS_BARRIER();
  }
  // ---- final store: step 63 outputs live in parity-0 buffers ----
  {
    const size_t ob = (size_t)b * LL + 63;
    if (tid < NE) {
      out[O_RE   + ob * NE + tid] = rbuf[0][tid];
      out[O_BALE + ob * NE + tid] = balbuf[0][tid];
    } else if (tid < NT) {
      const int j2 = tid - NE;
      out[O_RI   + ob * NI + j2] = rbuf[0][NE + j2];
      out[O_BALI + ob * NI + j2] = balbuf[0][NE + j2];
    }
  }
}

// ---------------------------------------------------------------------------
// Logits: [32768 x 128] @ Wro^T + bro. One thread per (m, class).
// ---------------------------------------------------------------------------
__global__ __launch_bounds__(256) void logits_kernel(const float* __restrict__ Wro,
                                                     const float* __restrict__ bro,
                                                     float* __restrict__ out) {
  __shared__ float WroL[NC * 132];   // row-stride 132 breaks bank alignment
  __shared__ float broL[NC];
  const int tid = threadIdx.x;
  for (int i = tid; i < NC * NE; i += 256) {
    int c = i >> 7, k = i & 127;
    WroL[c * 132 + k] = Wro[i];
  }
  if (tid < NC) broL[tid] = bro[tid];
  __syncthreads();
  const int idx = blockIdx.x * 256 + tid;   // 0..327679 exact
  const int m = idx / 10, c = idx - m * 10;
  const float* re = out + O_RE + (size_t)m * NE;
  float v = broL[c];
  #pragma unroll
  for (int t4 = 0; t4 < 32; ++t4) {
    float4 rv = *(const float4*)(re + t4 * 4);
    float4 wv = *(const float4*)(&WroL[c * 132 + t4 * 4]);
    v += rv.x * wv.x + rv.y * wv.y + rv.z * wv.z + rv.w * wv.w;
  }
  out[O_LOGITS + (size_t)m * NC + c] = v;
  if ((m & 63) == 63) out[O_LAST + (size_t)(m >> 6) * NC + c] = v;
}

extern "C" void kernel_launch(void* const* d_in, const int* in_sizes, int n_in,
                              void* d_out, int out_size, void* d_ws, size_t ws_size,
                              hipStream_t stream) {
  const float* x   = (const float*)d_in[0];
  const float* Wxe = (const float*)d_in[1];
  const float* Wxi = (const float*)d_in[2];
  const float* Wee = (const float*)d_in[3];
  const float* Wie = (const float*)d_in[4];
  const float* Wei = (const float*)d_in[5];
  const float* Wii = (const float*)d_in[6];
  const float* be  = (const float*)d_in[7];
  const float* bi  = (const float*)d_in[8];
  const float* Wro = (const float*)d_in[9];
  const float* bro = (const float*)d_in[10];
  float* ws  = (float*)d_ws;
  float* out = (float*)d_out;

  hipLaunchKernelGGL(prep_kernel, dim3((G_SZ + WT4_SZ + 255)/256), dim3(256), 0, stream,
                     Wxe, Wxi, Wee, Wie, Wei, Wii, ws);
  hipLaunchKernelGGL(gemm_kernel, dim3(MM/128), dim3(256), 0, stream,
                     x, ws, ws + U_OFF);
  hipLaunchKernelGGL(recur_kernel, dim3(BB), dim3(256), 0, stream,
                     ws, be, bi, out);
  hipLaunchKernelGGL(logits_kernel, dim3(MM * NC / 256), dim3(256), 0, stream,
                     Wro, bro, out);
}